// Round 1
// baseline (5383.863 us; speedup 1.0000x reference)
//
#include <hip/hip_runtime.h>
#include <math.h>

#define BB   4
#define TT   2048
#define DIMM 1024
#define NHH  16
#define HDD  64
#define MM   (BB * TT)  // 8192

// ---------------------------------------------------------------------------
// GEMM: C[M=8192, N=1024] = A @ W + bias      (W stored [K=1024, N=1024])
// ALAYOUT 0: A row-major [M,1024]
// ALAYOUT 1: A element (m,k) at [B,NH,T,HD]:
//            (((m>>11)*16 + (k>>6))*2048 + (m&2047))*64 + (k&63)
// OLAYOUT 0: C row-major [M,1024]
// OLAYOUT 1: C element (m,n) scattered to [B,NH,T,HD]
// 128x128 tile, BK=16, 256 threads, 8x8 per thread, reg-prefetch dbuf.
// ---------------------------------------------------------------------------
template <int ALAYOUT, int OLAYOUT>
__global__ __launch_bounds__(256, 2) void gemm_kernel(
    const float* __restrict__ A, const float* __restrict__ W,
    const float* __restrict__ bias, float* __restrict__ C)
{
    __shared__ float As[16][132];  // [k][m] transposed, padded stride 132
    __shared__ float Bs[16][128];  // [k][n]

    const int tid  = threadIdx.x;
    const int m0   = blockIdx.x * 128;
    const int n0   = blockIdx.y * 128;
    const int ty   = tid >> 4;         // 0..15  -> rows ty*8..+7
    const int tx   = tid & 15;         // 0..15  -> cols tx*8..+7
    const int rowa = tid >> 2;         // 0..63
    const int c4a  = (tid & 3) * 4;    // 0,4,8,12
    const int kb   = tid >> 5;         // 0..7
    const int n4b  = (tid & 31) * 4;   // 0..124

    float acc[8][8];
#pragma unroll
    for (int i = 0; i < 8; ++i)
#pragma unroll
        for (int j = 0; j < 8; ++j) acc[i][j] = 0.0f;

    float4 aR0, aR1, bR0, bR1;

    auto aidx = [&](int m, int k) -> int {
        if (ALAYOUT == 0) return m * 1024 + k;
        return (((m >> 11) * 16 + (k >> 6)) * 2048 + (m & 2047)) * 64 + (k & 63);
    };
    auto loadT = [&](int k0) {
        aR0 = *(const float4*)(A + aidx(m0 + rowa,      k0 + c4a));
        aR1 = *(const float4*)(A + aidx(m0 + rowa + 64, k0 + c4a));
        bR0 = *(const float4*)(W + (k0 + kb)     * 1024 + n0 + n4b);
        bR1 = *(const float4*)(W + (k0 + kb + 8) * 1024 + n0 + n4b);
    };
    auto storeT = [&]() {
        As[c4a + 0][rowa]      = aR0.x;
        As[c4a + 1][rowa]      = aR0.y;
        As[c4a + 2][rowa]      = aR0.z;
        As[c4a + 3][rowa]      = aR0.w;
        As[c4a + 0][rowa + 64] = aR1.x;
        As[c4a + 1][rowa + 64] = aR1.y;
        As[c4a + 2][rowa + 64] = aR1.z;
        As[c4a + 3][rowa + 64] = aR1.w;
        *(float4*)&Bs[kb][n4b]     = bR0;
        *(float4*)&Bs[kb + 8][n4b] = bR1;
    };

    loadT(0);
    storeT();
    __syncthreads();

    for (int kt = 0; kt < 64; ++kt) {
        if (kt < 63) loadT((kt + 1) * 16);
#pragma unroll
        for (int kk = 0; kk < 16; ++kk) {
            float4 a0 = *(float4*)&As[kk][ty * 8];
            float4 a1 = *(float4*)&As[kk][ty * 8 + 4];
            float4 b0 = *(float4*)&Bs[kk][tx * 8];
            float4 b1 = *(float4*)&Bs[kk][tx * 8 + 4];
            float av[8] = {a0.x, a0.y, a0.z, a0.w, a1.x, a1.y, a1.z, a1.w};
            float bw[8] = {b0.x, b0.y, b0.z, b0.w, b1.x, b1.y, b1.z, b1.w};
#pragma unroll
            for (int i = 0; i < 8; ++i)
#pragma unroll
                for (int j = 0; j < 8; ++j)
                    acc[i][j] = fmaf(av[i], bw[j], acc[i][j]);
        }
        __syncthreads();
        if (kt < 63) storeT();
        __syncthreads();
    }

    // epilogue: bias + store
#pragma unroll
    for (int i = 0; i < 8; ++i) {
        int m = m0 + ty * 8 + i;
#pragma unroll
        for (int jg = 0; jg < 2; ++jg) {
            int n = n0 + tx * 8 + jg * 4;
            float4 b4 = *(const float4*)(bias + n);
            float4 v;
            v.x = acc[i][jg * 4 + 0] + b4.x;
            v.y = acc[i][jg * 4 + 1] + b4.y;
            v.z = acc[i][jg * 4 + 2] + b4.z;
            v.w = acc[i][jg * 4 + 3] + b4.w;
            if (OLAYOUT == 0) {
                *(float4*)(C + m * 1024 + n) = v;
            } else {
                int b = m >> 11, t = m & 2047;
                int h = n >> 6,  d = n & 63;
                *(float4*)(C + (((b << 4) + h) * 2048 + t) * 64 + d) = v;
            }
        }
    }
}

// ---------------------------------------------------------------------------
// Flash attention, fp32. Block = 64 query rows of one (b,h). 256 threads.
// Q/K/V in [B,NH,T,HD]. Output written over the Q buffer rows this block
// consumed (each Q row read by exactly one block -> safe aliasing).
// Thread (tr,tc): 4x4 micro-tile, rows tr*4.., cols tc*4..
// ---------------------------------------------------------------------------
__global__ __launch_bounds__(256) void attn_kernel(
    const float* Qg, const float* __restrict__ Kg,
    const float* __restrict__ Vg, float* Og)
{
    __shared__ float Qst[64][68];  // [d][r], pre-scaled by 1/8
    __shared__ float KPs[64][68];  // K as [d][k]; reused as P [k][r]
    __shared__ float Vs[64][68];   // [k][d]

    const int tid = threadIdx.x;
    const int qt  = blockIdx.x & 31;   // T/64 = 32 q-tiles
    const int bh  = blockIdx.x >> 5;   // 0..63
    const float* Qp = Qg + bh * (TT * HDD) + qt * (64 * HDD);
    const float* Kp = Kg + bh * (TT * HDD);
    const float* Vp = Vg + bh * (TT * HDD);
    float*       Op = Og + bh * (TT * HDD) + qt * (64 * HDD);

    const int tr   = tid >> 4;       // 0..15
    const int tc   = tid & 15;       // 0..15
    const int srow = tid >> 2;       // 0..63
    const int sc4  = (tid & 3) * 4;  // 0,4,8,12

    const float scale = 0.125f;  // HD^-0.5 = 1/8

    // stage Q transposed + scaled
#pragma unroll
    for (int cc = 0; cc < 4; ++cc) {
        int d0 = sc4 + cc * 16;
        float4 q4 = *(const float4*)(Qp + srow * HDD + d0);
        Qst[d0 + 0][srow] = q4.x * scale;
        Qst[d0 + 1][srow] = q4.y * scale;
        Qst[d0 + 2][srow] = q4.z * scale;
        Qst[d0 + 3][srow] = q4.w * scale;
    }

    float o[4][4];
    float mrun[4], lrun[4];
#pragma unroll
    for (int i = 0; i < 4; ++i) {
        mrun[i] = -INFINITY;
        lrun[i] = 0.0f;
#pragma unroll
        for (int j = 0; j < 4; ++j) o[i][j] = 0.0f;
    }

    for (int kt = 0; kt < TT / 64; ++kt) {
        const float* Kpt = Kp + kt * (64 * HDD);
        const float* Vpt = Vp + kt * (64 * HDD);

        __syncthreads();  // prev-iter LDS reads done (also orders Q staging)
#pragma unroll
        for (int cc = 0; cc < 4; ++cc) {
            int d0 = sc4 + cc * 16;
            float4 k4 = *(const float4*)(Kpt + srow * HDD + d0);
            KPs[d0 + 0][srow] = k4.x;
            KPs[d0 + 1][srow] = k4.y;
            KPs[d0 + 2][srow] = k4.z;
            KPs[d0 + 3][srow] = k4.w;
            *(float4*)&Vs[srow][d0] = *(const float4*)(Vpt + srow * HDD + d0);
        }
        __syncthreads();

        // S = (Q*scale) @ K^T, 4x4 per thread
        float s[4][4];
#pragma unroll
        for (int i = 0; i < 4; ++i)
#pragma unroll
            for (int j = 0; j < 4; ++j) s[i][j] = 0.0f;
#pragma unroll 8
        for (int d = 0; d < 64; ++d) {
            float4 q4 = *(float4*)&Qst[d][tr * 4];
            float4 k4 = *(float4*)&KPs[d][tc * 4];
            float qa[4] = {q4.x, q4.y, q4.z, q4.w};
            float ka[4] = {k4.x, k4.y, k4.z, k4.w};
#pragma unroll
            for (int i = 0; i < 4; ++i)
#pragma unroll
                for (int j = 0; j < 4; ++j)
                    s[i][j] = fmaf(qa[i], ka[j], s[i][j]);
        }

        // online softmax: row reductions across the 16 tc-lanes (same wave)
        float mloc[4];
#pragma unroll
        for (int i = 0; i < 4; ++i)
            mloc[i] = fmaxf(fmaxf(s[i][0], s[i][1]), fmaxf(s[i][2], s[i][3]));
#pragma unroll
        for (int off = 1; off < 16; off <<= 1)
#pragma unroll
            for (int i = 0; i < 4; ++i)
                mloc[i] = fmaxf(mloc[i], __shfl_xor(mloc[i], off, 64));

        float p[4][4], resc[4], lloc[4];
#pragma unroll
        for (int i = 0; i < 4; ++i) {
            float mnew = fmaxf(mrun[i], mloc[i]);
            resc[i] = __expf(mrun[i] - mnew);
            mrun[i] = mnew;
#pragma unroll
            for (int j = 0; j < 4; ++j) p[i][j] = __expf(s[i][j] - mnew);
            lloc[i] = (p[i][0] + p[i][1]) + (p[i][2] + p[i][3]);
        }
#pragma unroll
        for (int off = 1; off < 16; off <<= 1)
#pragma unroll
            for (int i = 0; i < 4; ++i)
                lloc[i] += __shfl_xor(lloc[i], off, 64);
#pragma unroll
        for (int i = 0; i < 4; ++i) {
            lrun[i] = lrun[i] * resc[i] + lloc[i];
#pragma unroll
            for (int j = 0; j < 4; ++j) o[i][j] *= resc[i];
        }

        __syncthreads();  // all K reads done; safe to overwrite with P
        // write P transposed: Ps[k][r]
#pragma unroll
        for (int jj = 0; jj < 4; ++jj) {
            float4 pv;
            pv.x = p[0][jj]; pv.y = p[1][jj]; pv.z = p[2][jj]; pv.w = p[3][jj];
            *(float4*)&KPs[tc * 4 + jj][tr * 4] = pv;
        }
        __syncthreads();

        // O += P @ V
#pragma unroll 8
        for (int k = 0; k < 64; ++k) {
            float4 p4 = *(float4*)&KPs[k][tr * 4];
            float4 v4 = *(float4*)&Vs[k][tc * 4];
            float pa[4] = {p4.x, p4.y, p4.z, p4.w};
            float va[4] = {v4.x, v4.y, v4.z, v4.w};
#pragma unroll
            for (int i = 0; i < 4; ++i)
#pragma unroll
                for (int j = 0; j < 4; ++j)
                    o[i][j] = fmaf(pa[i], va[j], o[i][j]);
        }
    }

    // normalize + write back over the Q rows this block owns
#pragma unroll
    for (int i = 0; i < 4; ++i) {
        float inv = 1.0f / lrun[i];
        float4 v;
        v.x = o[i][0] * inv; v.y = o[i][1] * inv;
        v.z = o[i][2] * inv; v.w = o[i][3] * inv;
        *(float4*)(Op + (tr * 4 + i) * HDD + tc * 4) = v;
    }
}

extern "C" void kernel_launch(void* const* d_in, const int* in_sizes, int n_in,
                              void* d_out, int out_size, void* d_ws, size_t ws_size,
                              hipStream_t stream)
{
    const float* x  = (const float*)d_in[0];
    const float* Wq = (const float*)d_in[1];
    const float* bq = (const float*)d_in[2];
    const float* Wk = (const float*)d_in[3];
    const float* bk = (const float*)d_in[4];
    const float* Wv = (const float*)d_in[5];
    const float* bv = (const float*)d_in[6];
    const float* Wo = (const float*)d_in[7];
    const float* bo = (const float*)d_in[8];
    float* out = (float*)d_out;

    // ws: Q buffer + K buffer (33.5 MB each). V lives in d_out (overwritten
    // only by the final projection, which runs after attention completes).
    float* qb = (float*)d_ws;              // [B,NH,T,HD]; attn output aliases it
    float* kb = qb + (BB * TT * DIMM);     // 8388608 floats
    float* vb = out;                       // V staged in d_out

    dim3 grid(MM / 128, DIMM / 128);  // 64 x 8
    dim3 blk(256);

    gemm_kernel<0, 1><<<grid, blk, 0, stream>>>(x, Wq, bq, qb);
    gemm_kernel<0, 1><<<grid, blk, 0, stream>>>(x, Wk, bk, kb);
    gemm_kernel<0, 1><<<grid, blk, 0, stream>>>(x, Wv, bv, vb);

    attn_kernel<<<BB * NHH * (TT / 64), 256, 0, stream>>>(qb, kb, vb, qb);

    gemm_kernel<1, 0><<<grid, blk, 0, stream>>>(qb, Wo, bo, out);
}

// Round 2
// 1782.659 us; speedup vs baseline: 3.0201x; 3.0201x over previous
//
#include <hip/hip_runtime.h>
#include <math.h>

#define BB   4
#define TT   2048
#define DIMM 1024
#define NHH  16
#define HDD  64
#define MM   (BB * TT)  // 8192

// ---------------------------------------------------------------------------
// GEMM: C[M=8192, N=1024] = A @ W + bias      (W stored [K=1024, N=1024])
// ALAYOUT 0: A row-major [M,1024]
// ALAYOUT 1: A element (m,k) at [B,NH,T,HD]:
//            (((m>>11)*16 + (k>>6))*2048 + (m&2047))*64 + (k&63)
// OLAYOUT 0: C row-major [M,1024]
// OLAYOUT 1: C element (m,n) scattered to [B,NH,T,HD]
// 128x128 tile, BK=8, 256 threads, 8x8 micro-tile, LDS double-buffer.
// Register budget kept ~100 VGPR to avoid the round-1 spill catastrophe.
// ---------------------------------------------------------------------------
template <int ALAYOUT, int OLAYOUT>
__global__ __launch_bounds__(256, 2) void gemm_kernel(
    const float* __restrict__ A, const float* __restrict__ W,
    const float* __restrict__ bias, float* __restrict__ C)
{
    __shared__ float As[2][8][132];  // [buf][k][m] transposed, padded
    __shared__ float Bs[2][8][144];  // [buf][k][n'] col-swizzled

    const int tid = threadIdx.x;
    const int m0  = blockIdx.x * 128;
    const int n0  = blockIdx.y * 128;
    const int ty  = tid >> 4;          // 0..15 -> rows ty*8..+7
    const int tx  = tid & 15;          // 0..15 -> cols tx*8..+7

    // staging assignments (per kt, each thread: 1 float4 of A, 1 of B)
    const int am  = tid >> 1;          // 0..127 (A row within tile)
    const int ak  = (tid & 1) << 2;    // 0 or 4 (k offset)
    const int bk  = tid >> 5;          // 0..7   (B row = k)
    const int bn  = (tid & 31) << 2;   // 0..124 (B col, logical)
    const int bnp = bn + ((bn >> 5) << 2);   // swizzled physical col

    // compute-phase physical B columns (2-way max bank aliasing)
    const int c1 = tx * 8,     c2 = tx * 8 + 4;
    const int p1 = c1 + ((c1 >> 5) << 2);
    const int p2 = c2 + ((c2 >> 5) << 2);

    float acc[8][8];
#pragma unroll
    for (int i = 0; i < 8; ++i)
#pragma unroll
        for (int j = 0; j < 8; ++j) acc[i][j] = 0.0f;

    float4 aS, bS;  // staging registers (8 floats live across compute)

    auto aidx = [&](int m, int k) -> int {
        if (ALAYOUT == 0) return m * 1024 + k;
        return (((m >> 11) * 16 + (k >> 6)) * 2048 + (m & 2047)) * 64 + (k & 63);
    };
    auto gload = [&](int k0) {
        aS = *(const float4*)(A + aidx(m0 + am, k0 + ak));
        bS = *(const float4*)(W + (k0 + bk) * 1024 + n0 + bn);
    };
    auto sstore = [&](int b) {
        As[b][ak + 0][am] = aS.x;
        As[b][ak + 1][am] = aS.y;
        As[b][ak + 2][am] = aS.z;
        As[b][ak + 3][am] = aS.w;
        *(float4*)&Bs[b][bk][bnp] = bS;
    };

    gload(0);
    sstore(0);
    __syncthreads();

    int cur = 0;
    for (int kt = 0; kt < 128; ++kt) {
        if (kt < 127) gload((kt + 1) * 8);

        const float(*Asp)[132] = As[cur];
        const float(*Bsp)[144] = Bs[cur];
#pragma unroll
        for (int kk = 0; kk < 8; ++kk) {
            const float4 a0 = *(const float4*)&Asp[kk][ty * 8];
            const float4 a1 = *(const float4*)&Asp[kk][ty * 8 + 4];
            const float4 b0 = *(const float4*)&Bsp[kk][p1];
            const float4 b1 = *(const float4*)&Bsp[kk][p2];
#define GEMM_ROW(i, av)                                                        \
            acc[i][0] = fmaf(av, b0.x, acc[i][0]);                             \
            acc[i][1] = fmaf(av, b0.y, acc[i][1]);                             \
            acc[i][2] = fmaf(av, b0.z, acc[i][2]);                             \
            acc[i][3] = fmaf(av, b0.w, acc[i][3]);                             \
            acc[i][4] = fmaf(av, b1.x, acc[i][4]);                             \
            acc[i][5] = fmaf(av, b1.y, acc[i][5]);                             \
            acc[i][6] = fmaf(av, b1.z, acc[i][6]);                             \
            acc[i][7] = fmaf(av, b1.w, acc[i][7]);
            GEMM_ROW(0, a0.x) GEMM_ROW(1, a0.y) GEMM_ROW(2, a0.z) GEMM_ROW(3, a0.w)
            GEMM_ROW(4, a1.x) GEMM_ROW(5, a1.y) GEMM_ROW(6, a1.z) GEMM_ROW(7, a1.w)
#undef GEMM_ROW
        }

        if (kt < 127) sstore(cur ^ 1);  // write other buffer; no pre-sync needed
        __syncthreads();                // other buffer complete for next iter
        cur ^= 1;
    }

    // epilogue: bias + store
#pragma unroll
    for (int i = 0; i < 8; ++i) {
        int m = m0 + ty * 8 + i;
#pragma unroll
        for (int jg = 0; jg < 2; ++jg) {
            int n = n0 + tx * 8 + jg * 4;
            float4 b4 = *(const float4*)(bias + n);
            float4 v;
            v.x = acc[i][jg * 4 + 0] + b4.x;
            v.y = acc[i][jg * 4 + 1] + b4.y;
            v.z = acc[i][jg * 4 + 2] + b4.z;
            v.w = acc[i][jg * 4 + 3] + b4.w;
            if (OLAYOUT == 0) {
                *(float4*)(C + m * 1024 + n) = v;
            } else {
                int b = m >> 11, t = m & 2047;
                int h = n >> 6,  d = n & 63;
                *(float4*)(C + (((b << 4) + h) * 2048 + t) * 64 + d) = v;
            }
        }
    }
}

// ---------------------------------------------------------------------------
// Flash attention, fp32 (unchanged from passing round-1 version).
// Block = 64 query rows of one (b,h). 256 threads.
// ---------------------------------------------------------------------------
__global__ __launch_bounds__(256) void attn_kernel(
    const float* Qg, const float* __restrict__ Kg,
    const float* __restrict__ Vg, float* Og)
{
    __shared__ float Qst[64][68];  // [d][r], pre-scaled by 1/8
    __shared__ float KPs[64][68];  // K as [d][k]; reused as P [k][r]
    __shared__ float Vs[64][68];   // [k][d]

    const int tid = threadIdx.x;
    const int qt  = blockIdx.x & 31;
    const int bh  = blockIdx.x >> 5;
    const float* Qp = Qg + bh * (TT * HDD) + qt * (64 * HDD);
    const float* Kp = Kg + bh * (TT * HDD);
    const float* Vp = Vg + bh * (TT * HDD);
    float*       Op = Og + bh * (TT * HDD) + qt * (64 * HDD);

    const int tr   = tid >> 4;
    const int tc   = tid & 15;
    const int srow = tid >> 2;
    const int sc4  = (tid & 3) * 4;

    const float scale = 0.125f;

#pragma unroll
    for (int cc = 0; cc < 4; ++cc) {
        int d0 = sc4 + cc * 16;
        float4 q4 = *(const float4*)(Qp + srow * HDD + d0);
        Qst[d0 + 0][srow] = q4.x * scale;
        Qst[d0 + 1][srow] = q4.y * scale;
        Qst[d0 + 2][srow] = q4.z * scale;
        Qst[d0 + 3][srow] = q4.w * scale;
    }

    float o[4][4];
    float mrun[4], lrun[4];
#pragma unroll
    for (int i = 0; i < 4; ++i) {
        mrun[i] = -INFINITY;
        lrun[i] = 0.0f;
#pragma unroll
        for (int j = 0; j < 4; ++j) o[i][j] = 0.0f;
    }

    for (int kt = 0; kt < TT / 64; ++kt) {
        const float* Kpt = Kp + kt * (64 * HDD);
        const float* Vpt = Vp + kt * (64 * HDD);

        __syncthreads();
#pragma unroll
        for (int cc = 0; cc < 4; ++cc) {
            int d0 = sc4 + cc * 16;
            float4 k4 = *(const float4*)(Kpt + srow * HDD + d0);
            KPs[d0 + 0][srow] = k4.x;
            KPs[d0 + 1][srow] = k4.y;
            KPs[d0 + 2][srow] = k4.z;
            KPs[d0 + 3][srow] = k4.w;
            *(float4*)&Vs[srow][d0] = *(const float4*)(Vpt + srow * HDD + d0);
        }
        __syncthreads();

        float s[4][4];
#pragma unroll
        for (int i = 0; i < 4; ++i)
#pragma unroll
            for (int j = 0; j < 4; ++j) s[i][j] = 0.0f;
#pragma unroll 8
        for (int d = 0; d < 64; ++d) {
            float4 q4 = *(float4*)&Qst[d][tr * 4];
            float4 k4 = *(float4*)&KPs[d][tc * 4];
            float qa[4] = {q4.x, q4.y, q4.z, q4.w};
            float ka[4] = {k4.x, k4.y, k4.z, k4.w};
#pragma unroll
            for (int i = 0; i < 4; ++i)
#pragma unroll
                for (int j = 0; j < 4; ++j)
                    s[i][j] = fmaf(qa[i], ka[j], s[i][j]);
        }

        float mloc[4];
#pragma unroll
        for (int i = 0; i < 4; ++i)
            mloc[i] = fmaxf(fmaxf(s[i][0], s[i][1]), fmaxf(s[i][2], s[i][3]));
#pragma unroll
        for (int off = 1; off < 16; off <<= 1)
#pragma unroll
            for (int i = 0; i < 4; ++i)
                mloc[i] = fmaxf(mloc[i], __shfl_xor(mloc[i], off, 64));

        float p[4][4], resc[4], lloc[4];
#pragma unroll
        for (int i = 0; i < 4; ++i) {
            float mnew = fmaxf(mrun[i], mloc[i]);
            resc[i] = __expf(mrun[i] - mnew);
            mrun[i] = mnew;
#pragma unroll
            for (int j = 0; j < 4; ++j) p[i][j] = __expf(s[i][j] - mnew);
            lloc[i] = (p[i][0] + p[i][1]) + (p[i][2] + p[i][3]);
        }
#pragma unroll
        for (int off = 1; off < 16; off <<= 1)
#pragma unroll
            for (int i = 0; i < 4; ++i)
                lloc[i] += __shfl_xor(lloc[i], off, 64);
#pragma unroll
        for (int i = 0; i < 4; ++i) {
            lrun[i] = lrun[i] * resc[i] + lloc[i];
#pragma unroll
            for (int j = 0; j < 4; ++j) o[i][j] *= resc[i];
        }

        __syncthreads();
#pragma unroll
        for (int jj = 0; jj < 4; ++jj) {
            float4 pv;
            pv.x = p[0][jj]; pv.y = p[1][jj]; pv.z = p[2][jj]; pv.w = p[3][jj];
            *(float4*)&KPs[tc * 4 + jj][tr * 4] = pv;
        }
        __syncthreads();

#pragma unroll 8
        for (int k = 0; k < 64; ++k) {
            float4 p4 = *(float4*)&KPs[k][tr * 4];
            float4 v4 = *(float4*)&Vs[k][tc * 4];
            float pa[4] = {p4.x, p4.y, p4.z, p4.w};
            float va[4] = {v4.x, v4.y, v4.z, v4.w};
#pragma unroll
            for (int i = 0; i < 4; ++i)
#pragma unroll
                for (int j = 0; j < 4; ++j)
                    o[i][j] = fmaf(pa[i], va[j], o[i][j]);
        }
    }

#pragma unroll
    for (int i = 0; i < 4; ++i) {
        float inv = 1.0f / lrun[i];
        float4 v;
        v.x = o[i][0] * inv; v.y = o[i][1] * inv;
        v.z = o[i][2] * inv; v.w = o[i][3] * inv;
        *(float4*)(Op + (tr * 4 + i) * HDD + tc * 4) = v;
    }
}

extern "C" void kernel_launch(void* const* d_in, const int* in_sizes, int n_in,
                              void* d_out, int out_size, void* d_ws, size_t ws_size,
                              hipStream_t stream)
{
    const float* x  = (const float*)d_in[0];
    const float* Wq = (const float*)d_in[1];
    const float* bq = (const float*)d_in[2];
    const float* Wk = (const float*)d_in[3];
    const float* bk = (const float*)d_in[4];
    const float* Wv = (const float*)d_in[5];
    const float* bv = (const float*)d_in[6];
    const float* Wo = (const float*)d_in[7];
    const float* bo = (const float*)d_in[8];
    float* out = (float*)d_out;

    // ws: Q buffer + K buffer (33.5 MB each). V lives in d_out (overwritten
    // only by the final projection, which runs after attention completes).
    float* qb = (float*)d_ws;              // [B,NH,T,HD]; attn output aliases it
    float* kb = qb + (BB * TT * DIMM);
    float* vb = out;                       // V staged in d_out

    dim3 grid(MM / 128, DIMM / 128);  // 64 x 8
    dim3 blk(256);

    gemm_kernel<0, 1><<<grid, blk, 0, stream>>>(x, Wq, bq, qb);
    gemm_kernel<0, 1><<<grid, blk, 0, stream>>>(x, Wk, bk, kb);
    gemm_kernel<0, 1><<<grid, blk, 0, stream>>>(x, Wv, bv, vb);

    attn_kernel<<<BB * NHH * (TT / 64), 256, 0, stream>>>(qb, kb, vb, qb);

    gemm_kernel<1, 0><<<grid, blk, 0, stream>>>(qb, Wo, bo, out);
}

// Round 3
// 357.402 us; speedup vs baseline: 15.0639x; 4.9878x over previous
//
#include <hip/hip_runtime.h>
#include <math.h>

#define BB   4
#define TT   2048
#define DIMM 1024
#define NHH  16
#define HDD  64
#define MM   (BB * TT)  // 8192

typedef unsigned short u16;
typedef unsigned int   u32;
typedef short bf16x8 __attribute__((ext_vector_type(8)));  // 8 bf16 = 4 VGPRs
typedef float f32x4  __attribute__((ext_vector_type(4)));

__device__ __forceinline__ u16 f2bf(float f) {  // round-to-nearest-even
    u32 u = __float_as_uint(f);
    return (u16)((u + 0x7fffu + ((u >> 16) & 1u)) >> 16);
}

__device__ __forceinline__ f32x4 mfma16(bf16x8 a, bf16x8 b, f32x4 c) {
    return __builtin_amdgcn_mfma_f32_16x16x32_bf16(a, b, c, 0, 0, 0);
}

// swizzle for 128-byte-stride LDS rows (64 bf16/row, 8 slots of 16B):
// phys slot = slot ^ (row&7) ^ ((row>>3)&7). Returns u16 offset within row.
__device__ __forceinline__ int swz8(int row, int slot) {
    return ((slot ^ (row & 7) ^ ((row >> 3) & 7)) & 7) * 8;
}
// swizzle for 64-byte-stride LDS rows (32 bf16/row, 4 slots of 16B)
__device__ __forceinline__ int swz4(int row, int slot) {
    return ((slot ^ (row & 3)) & 3) * 8;
}

// ---------------------------------------------------------------------------
// fp32 -> bf16 straight convert (x). n must be multiple of 2048*8.
// ---------------------------------------------------------------------------
__global__ void convert_x_bf16(const float* __restrict__ in, u16* __restrict__ out) {
    int i = (blockIdx.x * 256 + threadIdx.x) * 8;
    float4 a = *(const float4*)(in + i);
    float4 b = *(const float4*)(in + i + 4);
    u32 w0 = f2bf(a.x) | ((u32)f2bf(a.y) << 16);
    u32 w1 = f2bf(a.z) | ((u32)f2bf(a.w) << 16);
    u32 w2 = f2bf(b.x) | ((u32)f2bf(b.y) << 16);
    u32 w3 = f2bf(b.z) | ((u32)f2bf(b.w) << 16);
    uint4 o = make_uint4(w0, w1, w2, w3);
    *(uint4*)(out + i) = o;
}

// ---------------------------------------------------------------------------
// W[k][n] fp32 -> Wt[n][k] bf16 (1024x1024), 32x32 LDS tile transpose.
// ---------------------------------------------------------------------------
__global__ void transpose_w_bf16(const float* __restrict__ W, u16* __restrict__ Wt) {
    __shared__ float tile[32][33];
    const int c  = threadIdx.x & 31;
    const int r8 = threadIdx.x >> 5;   // 0..7
    const int kb = blockIdx.y * 32, nb = blockIdx.x * 32;
#pragma unroll
    for (int rr = 0; rr < 4; ++rr) {
        int r = r8 + rr * 8;
        tile[r][c] = W[(kb + r) * 1024 + nb + c];
    }
    __syncthreads();
#pragma unroll
    for (int rr = 0; rr < 4; ++rr) {
        int r = r8 + rr * 8;
        Wt[(nb + r) * 1024 + kb + c] = f2bf(tile[c][r]);
    }
}

// ---------------------------------------------------------------------------
// bf16 MFMA GEMM: C[8192,1024] = A @ W + bias, W given transposed Bt[n][k].
// 128x128 tile, BK=32, 256 thr = 4 waves, each wave 64x64 (4x4 16x16 frags).
// OLAYOUT 0: fp32 row-major out.  OLAYOUT 1: bf16 scatter to [b,h,t,d], *oscale.
// ---------------------------------------------------------------------------
template <int OLAYOUT>
__global__ __launch_bounds__(256, 2) void gemm_bf16(
    const u16* __restrict__ A, const u16* __restrict__ Bt,
    const float* __restrict__ bias, void* __restrict__ Cout, float oscale)
{
    __shared__ u16 As[128 * 32];
    __shared__ u16 Bs[128 * 32];

    const int tid  = threadIdx.x;
    const int m0   = blockIdx.x * 128;
    const int n0   = blockIdx.y * 128;
    const int wave = tid >> 6, lane = tid & 63;
    const int wr = wave >> 1, wc = wave & 1;
    const int l15 = lane & 15, l4 = lane >> 4;

    // staging: slots s0=tid, s1=tid+256; row = s>>2 (0..127), kslot = s&3
    const int r0 = tid >> 2, ks = tid & 3;
    const int r1 = r0 + 64;
    const int w0 = r0 * 32 + swz4(r0, ks);
    const int w1 = r1 * 32 + swz4(r1, ks);

    f32x4 acc[4][4];
#pragma unroll
    for (int i = 0; i < 4; ++i)
#pragma unroll
        for (int j = 0; j < 4; ++j) acc[i][j] = (f32x4){0.f, 0.f, 0.f, 0.f};

    const u16* Ar0 = A  + (m0 + r0) * 1024 + ks * 8;
    const u16* Ar1 = A  + (m0 + r1) * 1024 + ks * 8;
    const u16* Br0 = Bt + (n0 + r0) * 1024 + ks * 8;
    const u16* Br1 = Bt + (n0 + r1) * 1024 + ks * 8;

    uint4 a0 = *(const uint4*)Ar0;
    uint4 a1 = *(const uint4*)Ar1;
    uint4 b0 = *(const uint4*)Br0;
    uint4 b1 = *(const uint4*)Br1;
    *(uint4*)&As[w0] = a0; *(uint4*)&As[w1] = a1;
    *(uint4*)&Bs[w0] = b0; *(uint4*)&Bs[w1] = b1;
    __syncthreads();

    for (int kt = 0; kt < 32; ++kt) {
        if (kt < 31) {
            const int ko = (kt + 1) * 32;
            a0 = *(const uint4*)(Ar0 + ko);
            a1 = *(const uint4*)(Ar1 + ko);
            b0 = *(const uint4*)(Br0 + ko);
            b1 = *(const uint4*)(Br1 + ko);
        }
        bf16x8 af[4], bf[4];
#pragma unroll
        for (int rt = 0; rt < 4; ++rt) {
            int row = wr * 64 + rt * 16 + l15;
            af[rt] = *(const bf16x8*)&As[row * 32 + swz4(row, l4)];
            int col = wc * 64 + rt * 16 + l15;
            bf[rt] = *(const bf16x8*)&Bs[col * 32 + swz4(col, l4)];
        }
#pragma unroll
        for (int rt = 0; rt < 4; ++rt)
#pragma unroll
            for (int ct = 0; ct < 4; ++ct)
                acc[rt][ct] = mfma16(af[rt], bf[ct], acc[rt][ct]);
        __syncthreads();
        if (kt < 31) {
            *(uint4*)&As[w0] = a0; *(uint4*)&As[w1] = a1;
            *(uint4*)&Bs[w0] = b0; *(uint4*)&Bs[w1] = b1;
            __syncthreads();
        }
    }

    // epilogue: C/D layout col = lane&15, row = (lane>>4)*4 + i
#pragma unroll
    for (int rt = 0; rt < 4; ++rt)
#pragma unroll
        for (int ct = 0; ct < 4; ++ct) {
            int n = n0 + wc * 64 + ct * 16 + l15;
            float bn = bias[n];
#pragma unroll
            for (int i = 0; i < 4; ++i) {
                int m = m0 + wr * 64 + rt * 16 + l4 * 4 + i;
                float v = (acc[rt][ct][i] + bn) * oscale;
                if (OLAYOUT == 0) {
                    ((float*)Cout)[m * 1024 + n] = v;
                } else {
                    int b = m >> 11, t = m & 2047;
                    int h = n >> 6,  d = n & 63;
                    ((u16*)Cout)[(((b << 4) + h) * 2048 + t) * 64 + d] = f2bf(v);
                }
            }
        }
}

// ---------------------------------------------------------------------------
// MFMA flash attention (bf16 inputs, fp32 accumulate).
// Block = 128 q-rows of one (b,h); 256 thr = 4 waves, wave owns 32 q-rows
// (2 16-row tiles). KV tiles of 64. Q pre-scaled by 1/8 in the Q-GEMM.
// Output bf16, row-major [8192][1024] (t-major, head cols) for the out-proj.
// ---------------------------------------------------------------------------
__global__ __launch_bounds__(256) void attn_mfma(
    const u16* __restrict__ Qb, const u16* __restrict__ Kb,
    const u16* __restrict__ Vb, u16* __restrict__ Ob)
{
    __shared__ u16 Ks[64 * 64];       // [key][d], swizzled
    __shared__ u16 Vts[64 * 64];      // [d][key], swizzled
    __shared__ u16 Ps[4][32 * 64];    // per-wave [q][key], swizzled

    const int tid  = threadIdx.x;
    const int bh   = blockIdx.x >> 4;
    const int q0   = (blockIdx.x & 15) * 128;
    const int b    = bh >> 4, h = bh & 15;
    const u16* Qp  = Qb + (bh * TT + q0) * HDD;
    const u16* Kp  = Kb + bh * TT * HDD;
    const u16* Vp  = Vb + bh * TT * HDD;

    const int wave = tid >> 6, lane = tid & 63;
    const int l15 = lane & 15, l4 = lane >> 4;

    // Q fragments: A-frag lane holds Q[m=lane&15][k=(lane>>4)*8+i], halves k0/k32
    bf16x8 qf[2][2];
#pragma unroll
    for (int qt = 0; qt < 2; ++qt)
#pragma unroll
        for (int hf = 0; hf < 2; ++hf)
            qf[qt][hf] = *(const bf16x8*)(Qp + (wave * 32 + qt * 16 + l15) * HDD
                                          + hf * 32 + l4 * 8);

    f32x4 oacc[2][4];
    float mr[2][4], lr[2][4];
#pragma unroll
    for (int qt = 0; qt < 2; ++qt)
#pragma unroll
        for (int i = 0; i < 4; ++i) {
            mr[qt][i] = -INFINITY; lr[qt][i] = 0.f;
            oacc[qt][i] = (f32x4){0.f, 0.f, 0.f, 0.f};
        }

    // staging: slot s0=tid -> key=s>>3 (0..31), dslot=s&7; s1=tid+256 -> keys 32..63
    const int key0 = tid >> 3, ds = tid & 7;
    const int key1 = key0 + 32;
    const int kwo0 = key0 * 64 + swz8(key0, ds);
    const int kwo1 = key1 * 64 + swz8(key1, ds);

    for (int kv = 0; kv < TT / 64; ++kv) {
        const u16* Kt = Kp + kv * 64 * HDD;
        const u16* Vt = Vp + kv * 64 * HDD;

        __syncthreads();  // previous tile's LDS reads complete
        *(uint4*)&Ks[kwo0] = *(const uint4*)(Kt + key0 * 64 + ds * 8);
        *(uint4*)&Ks[kwo1] = *(const uint4*)(Kt + key1 * 64 + ds * 8);
        {
            uint4 vv0 = *(const uint4*)(Vt + key0 * 64 + ds * 8);
            uint4 vv1 = *(const uint4*)(Vt + key1 * 64 + ds * 8);
            const u16* e0 = (const u16*)&vv0;
            const u16* e1 = (const u16*)&vv1;
#pragma unroll
            for (int j = 0; j < 8; ++j) {
                int d0 = ds * 8 + j;
                Vts[d0 * 64 + swz8(d0, key0 >> 3) + (key0 & 7)] = e0[j];
                Vts[d0 * 64 + swz8(d0, key1 >> 3) + (key1 & 7)] = e1[j];
            }
        }
        __syncthreads();  // staging complete

        // ---- S = Q @ K^T  (B-frag lane holds K[key=lane&15][k=(lane>>4)*8+i]) ----
        f32x4 sacc[2][4];
#pragma unroll
        for (int qt = 0; qt < 2; ++qt)
#pragma unroll
            for (int nt = 0; nt < 4; ++nt) sacc[qt][nt] = (f32x4){0.f, 0.f, 0.f, 0.f};
#pragma unroll
        for (int nt = 0; nt < 4; ++nt) {
            int krow = nt * 16 + l15;
#pragma unroll
            for (int hf = 0; hf < 2; ++hf) {
                bf16x8 kf = *(const bf16x8*)&Ks[krow * 64 + swz8(krow, l4 + hf * 4)];
                sacc[0][nt] = mfma16(qf[0][hf], kf, sacc[0][nt]);
                sacc[1][nt] = mfma16(qf[1][hf], kf, sacc[1][nt]);
            }
        }

        // ---- online softmax (rows: q = qt*16 + l4*4 + i; cols across 16 lanes) ----
#pragma unroll
        for (int qt = 0; qt < 2; ++qt) {
            float mloc[4], lsum[4];
#pragma unroll
            for (int i = 0; i < 4; ++i)
                mloc[i] = fmaxf(fmaxf(sacc[qt][0][i], sacc[qt][1][i]),
                                fmaxf(sacc[qt][2][i], sacc[qt][3][i]));
#pragma unroll
            for (int off = 1; off < 16; off <<= 1)
#pragma unroll
                for (int i = 0; i < 4; ++i)
                    mloc[i] = fmaxf(mloc[i], __shfl_xor(mloc[i], off, 64));
#pragma unroll
            for (int i = 0; i < 4; ++i) {
                float mnew = fmaxf(mr[qt][i], mloc[i]);
                float rsc  = __expf(mr[qt][i] - mnew);
                mr[qt][i]  = mnew;
                lr[qt][i] *= rsc;
#pragma unroll
                for (int db = 0; db < 4; ++db) oacc[qt][db][i] *= rsc;
                lsum[i] = 0.f;
            }
#pragma unroll
            for (int nt = 0; nt < 4; ++nt) {
                int key = nt * 16 + l15;
#pragma unroll
                for (int i = 0; i < 4; ++i) {
                    float pv = __expf(sacc[qt][nt][i] - mr[qt][i]);
                    lsum[i] += pv;
                    int q = qt * 16 + l4 * 4 + i;
                    Ps[wave][q * 64 + swz8(q, key >> 3) + (key & 7)] = f2bf(pv);
                }
            }
#pragma unroll
            for (int off = 1; off < 16; off <<= 1)
#pragma unroll
                for (int i = 0; i < 4; ++i)
                    lsum[i] += __shfl_xor(lsum[i], off, 64);
#pragma unroll
            for (int i = 0; i < 4; ++i) lr[qt][i] += lsum[i];
        }

        // ---- O += P @ V ----
        bf16x8 pf[2][2];
#pragma unroll
        for (int qt = 0; qt < 2; ++qt)
#pragma unroll
            for (int hf = 0; hf < 2; ++hf) {
                int q = qt * 16 + l15;
                pf[qt][hf] = *(const bf16x8*)&Ps[wave][q * 64 + swz8(q, l4 + hf * 4)];
            }
#pragma unroll
        for (int db = 0; db < 4; ++db) {
            int d = db * 16 + l15;
#pragma unroll
            for (int hf = 0; hf < 2; ++hf) {
                bf16x8 vf = *(const bf16x8*)&Vts[d * 64 + swz8(d, l4 + hf * 4)];
                oacc[0][db] = mfma16(pf[0][hf], vf, oacc[0][db]);
                oacc[1][db] = mfma16(pf[1][hf], vf, oacc[1][db]);
            }
        }
    }

    // epilogue: normalize, write bf16 row-major [b*2048+t][h*64+d]
#pragma unroll
    for (int qt = 0; qt < 2; ++qt) {
        float inv[4];
#pragma unroll
        for (int i = 0; i < 4; ++i) inv[i] = 1.f / lr[qt][i];
#pragma unroll
        for (int db = 0; db < 4; ++db)
#pragma unroll
            for (int i = 0; i < 4; ++i) {
                int t   = q0 + wave * 32 + qt * 16 + l4 * 4 + i;
                int col = h * 64 + db * 16 + l15;
                Ob[(b * TT + t) * DIMM + col] = f2bf(oacc[qt][db][i] * inv[i]);
            }
    }
}

extern "C" void kernel_launch(void* const* d_in, const int* in_sizes, int n_in,
                              void* d_out, int out_size, void* d_ws, size_t ws_size,
                              hipStream_t stream)
{
    const float* x  = (const float*)d_in[0];
    const float* Wq = (const float*)d_in[1];
    const float* bq = (const float*)d_in[2];
    const float* Wk = (const float*)d_in[3];
    const float* bk = (const float*)d_in[4];
    const float* Wv = (const float*)d_in[5];
    const float* bv = (const float*)d_in[6];
    const float* Wo = (const float*)d_in[7];
    const float* bo = (const float*)d_in[8];

    // ws layout (bf16): xb | Wq^T Wk^T Wv^T Wo^T | qbuf | obuf  (~58.8 MB)
    u16* xb   = (u16*)d_ws;              // 8192*1024
    u16* wqt  = xb   + 8388608;          // 1024*1024 each
    u16* wkt  = wqt  + 1048576;
    u16* wvt  = wkt  + 1048576;
    u16* wot  = wvt  + 1048576;
    u16* qbuf = wot  + 1048576;          // [64 bh][2048][64], pre-scaled by 1/8
    u16* obuf = qbuf + 8388608;          // [8192][1024]
    // K and V (bf16) live inside d_out (exactly 2 x 16.78 MB = 33.55 MB);
    // the final projection overwrites d_out only after attention consumed them.
    u16* kbuf = (u16*)d_out;
    u16* vbuf = kbuf + 8388608;

    convert_x_bf16<<<4096, 256, 0, stream>>>(x, xb);
    transpose_w_bf16<<<dim3(32, 32), 256, 0, stream>>>(Wq, wqt);
    transpose_w_bf16<<<dim3(32, 32), 256, 0, stream>>>(Wk, wkt);
    transpose_w_bf16<<<dim3(32, 32), 256, 0, stream>>>(Wv, wvt);
    transpose_w_bf16<<<dim3(32, 32), 256, 0, stream>>>(Wo, wot);

    dim3 gg(MM / 128, DIMM / 128);  // 64 x 8
    gemm_bf16<1><<<gg, 256, 0, stream>>>(xb, wqt, bq, qbuf, 0.125f);
    gemm_bf16<1><<<gg, 256, 0, stream>>>(xb, wkt, bk, kbuf, 1.0f);
    gemm_bf16<1><<<gg, 256, 0, stream>>>(xb, wvt, bv, vbuf, 1.0f);

    attn_mfma<<<BB * NHH * (TT / 128), 256, 0, stream>>>(qbuf, kbuf, vbuf, obuf);

    gemm_bf16<0><<<gg, 256, 0, stream>>>(obuf, wot, bo, d_out, 1.0f);
}